// Round 9
// baseline (186.408 us; speedup 1.0000x reference)
//
#include <hip/hip_runtime.h>
#include <stdint.h>

// DotProductAttention, B=8 S=4096 D=64 fp32, key-masked at valid_len[b].
// v6: occupancy-supply fix.
//  - prepack (verified): K,V -> bf16 hi/lo 16KB tiles per 32-key chunk in ws.
//  - attn: block = 64 Q-rows x 2 waves (wave = 32 rows); shared 2x16KB LDS
//    chunk double-buffer -> 5 blocks/CU x 2 waves = 10 waves/CU sustained.
//    Balanced key slicing (slice s: chunks [s*nch/nsl,(s+1)*nch/nsl)), NO
//    early exit -> all 2048 blocks active; 1.6x oversubscription of the 1280
//    resident slots gives the HW dispatcher refill slack. b=blk&7 mixes
//    batches across each CU.
//  - body per iteration is v5's verified code: swapped QK^T (mfma(K,Q)),
//    error-compensated bf16 hi/lo, in-register P via cvt_pk+permlane32_swap,
//    defer-max online softmax. Partials always written; combine merges.

constexpr int BB = 8;
constexpr int SS = 4096;
constexpr int DH = 64;
constexpr int CH = 32;              // keys per chunk
constexpr int NKT = SS / CH;        // 128 chunks per batch
constexpr int TILE_SHORTS = 8192;   // 16 KB: Khi 4K | Klo 4K | Vhi 4K | Vlo 4K
constexpr int TPB = BB * (SS / 64); // 512 output tiles of 64 rows
constexpr int NSL = 4;              // key slices per tile

typedef short  bfrag  __attribute__((ext_vector_type(8)));   // 8 bf16
typedef float  f32x16 __attribute__((ext_vector_type(16)));
typedef unsigned int uvec4 __attribute__((ext_vector_type(4)));

__device__ __forceinline__ unsigned short f2bf(float x) {
  unsigned u = __builtin_bit_cast(unsigned, x);
  u += 0x7fffu + ((u >> 16) & 1u);   // RNE
  return (unsigned short)(u >> 16);
}
__device__ __forceinline__ float bf2f(unsigned short h) {
  return __builtin_bit_cast(float, ((unsigned)h) << 16);
}

// ---------------- pre-pass: split+tile K and V (verified) ----------------
__global__ __launch_bounds__(256) void prepack(
    const float* __restrict__ K, const float* __restrict__ V,
    short* __restrict__ ws) {
  const int b  = blockIdx.x >> 7;
  const int kt = blockIdx.x & 127;
  const int t  = threadIdx.x;
  short* tile = ws + (size_t)(b * NKT + kt) * TILE_SHORTS;

  {  // K unit t: d8 = t>>5, key = t&31
    const int d8 = t >> 5, key = t & 31;
    const float* src = K + ((size_t)b * SS + kt * CH + key) * DH + d8 * 8;
    float4 a = ((const float4*)src)[0];
    float4 c = ((const float4*)src)[1];
    float v[8] = {a.x, a.y, a.z, a.w, c.x, c.y, c.z, c.w};
    bfrag hi, lo;
#pragma unroll
    for (int j = 0; j < 8; ++j) {
      unsigned short h = f2bf(v[j]);
      hi[j] = (short)h;
      lo[j] = (short)f2bf(v[j] - bf2f(h));
    }
    *(bfrag*)(tile + t * 8)        = hi;
    *(bfrag*)(tile + 2048 + t * 8) = lo;
  }
  {  // V unit t: k8 = t>>6, d = t&63
    const int k8 = t >> 6, d = t & 63;
    const float* src = V + ((size_t)b * SS + kt * CH + k8 * 8) * DH + d;
    bfrag hi, lo;
#pragma unroll
    for (int j = 0; j < 8; ++j) {
      float x = src[j * DH];
      unsigned short h = f2bf(x);
      hi[j] = (short)h;
      lo[j] = (short)f2bf(x - bf2f(h));
    }
    *(bfrag*)(tile + 4096 + t * 8) = hi;
    *(bfrag*)(tile + 6144 + t * 8) = lo;
  }
}

// ---------------- main fused attention ----------------
__global__ __launch_bounds__(128, 4) void attn_mfma(
    const float* __restrict__ Q, const short* __restrict__ wsT,
    const int* __restrict__ VL, float* __restrict__ Out,
    float* __restrict__ part_o, float* __restrict__ part_ml, int nsl) {
  __shared__ __align__(16) short sKV[2][TILE_SHORTS];  // 32 KB double buffer

  const int blk = blockIdx.x;
  const int b    = blk & 7;          // consecutive blocks -> different batches
  const int rest = blk >> 3;         // (qt, slice)
  const int qt    = rest / nsl;      // 0..63 (64-row tile)
  const int slice = rest % nsl;
  const int tid = threadIdx.x;
  const int w   = tid >> 6;   // wave = row group (w*32 rows)
  const int l   = tid & 63;
  const int hi5 = l >> 5;
  const int l31 = l & 31;

  const int vlen = VL[b];
  const int nch  = (vlen + CH - 1) / CH;
  // balanced slicing: every block active, work proportional to vlen
  const int c_lo = slice * nch / nsl;
  const int c_hi = (slice + 1) * nch / nsl;
  const int nchS = c_hi - c_lo;

  // ---- Q fragments (B-operand: col=l31=q-row), pre-scaled by 1/8 ----
  bfrag qh[4], ql[4];
  {
    const float* qsrc = Q + ((size_t)b * SS + qt * 64 + w * 32 + l31) * DH;
#pragma unroll
    for (int dt = 0; dt < 4; ++dt) {
      const float* pp = qsrc + dt * 16 + hi5 * 8;
      float4 a = ((const float4*)pp)[0];
      float4 c = ((const float4*)pp)[1];
      float v[8] = {a.x, a.y, a.z, a.w, c.x, c.y, c.z, c.w};
#pragma unroll
      for (int j = 0; j < 8; ++j) {
        float x = v[j] * 0.125f;
        unsigned short h = f2bf(x);
        qh[dt][j] = (short)h;
        ql[dt][j] = (short)f2bf(x - bf2f(h));
      }
    }
  }

  f32x16 o0, o1;
#pragma unroll
  for (int r = 0; r < 16; ++r) { o0[r] = 0.f; o1[r] = 0.f; }
  float m = -1e30f, lsum = 0.f;

  const short* tbase = wsT + (size_t)b * NKT * TILE_SHORTS;

  // stage chunk ci (16KB) into sKV[buf]: 8 passes x (128 thr x 16B)
  auto stage = [&](int ci, int buf) {
    const short* g = tbase + (size_t)ci * TILE_SHORTS;
#pragma unroll
    for (int j = 0; j < 8; ++j) {
      __builtin_amdgcn_global_load_lds(
          (const __attribute__((address_space(1))) void*)(g + (j * 128 + tid) * 8),
          (__attribute__((address_space(3))) void*)(&sKV[buf][(j * 128 + tid) * 8]),
          16, 0, 0);
    }
  };

  if (nchS > 0) stage(c_lo, 0);

  for (int t = 0; t < nchS; ++t) {
    __syncthreads();  // implicit vmcnt(0)+lgkmcnt(0): staged chunk ready
    const int ci  = c_lo + t;
    const int cur = t & 1;
    if (t + 1 < nchS) stage(ci + 1, cur ^ 1);  // prefetch under compute
    const short* t0 = &sKV[cur][0];

    // ---- QK^T: acc[key][qrow], A=K B=Q; two 6-chains ----
    f32x16 accA, accB;
#pragma unroll
    for (int r = 0; r < 16; ++r) { accA[r] = 0.f; accB[r] = 0.f; }
#pragma unroll
    for (int dt = 0; dt < 4; ++dt) {
      bfrag kh = *(const bfrag*)(t0 + ((2 * dt + hi5) * 32 + l31) * 8);
      bfrag kl = *(const bfrag*)(t0 + 2048 + ((2 * dt + hi5) * 32 + l31) * 8);
      accA = __builtin_amdgcn_mfma_f32_32x32x16_bf16(kh, qh[dt], accA, 0, 0, 0);
      if (dt < 2)
        accA = __builtin_amdgcn_mfma_f32_32x32x16_bf16(kh, ql[dt], accA, 0, 0, 0);
      else
        accB = __builtin_amdgcn_mfma_f32_32x32x16_bf16(kh, ql[dt], accB, 0, 0, 0);
      accB = __builtin_amdgcn_mfma_f32_32x32x16_bf16(kl, qh[dt], accB, 0, 0, 0);
    }
    float s[16];
#pragma unroll
    for (int r = 0; r < 16; ++r) s[r] = accA[r] + accB[r];

    // ---- mask tail keys ----
    const int c0 = ci * CH;
    if (c0 + CH > vlen) {
#pragma unroll
      for (int r = 0; r < 16; ++r) {
        int key = c0 + (r & 3) + 8 * (r >> 2) + 4 * hi5;
        if (key >= vlen) s[r] = -1e30f;
      }
    }

    // ---- online softmax (lane owns q-row l31) ----
    float cmax = s[0];
#pragma unroll
    for (int r = 1; r < 16; ++r) cmax = fmaxf(cmax, s[r]);
    cmax = fmaxf(cmax, __shfl_xor(cmax, 32));

    if (__any((int)(cmax > m + 8.0f))) {  // defer-max (T13)
      float mn = fmaxf(m, cmax);
      float sc2 = __expf(m - mn);
      m = mn;
      lsum *= sc2;
#pragma unroll
      for (int r = 0; r < 16; ++r) {
        float s2 = __shfl(sc2, (r & 3) + 8 * (r >> 2) + 4 * hi5);
        o0[r] *= s2;
        o1[r] *= s2;
      }
    }

    float ps = 0.f;
#pragma unroll
    for (int r = 0; r < 16; ++r) {
      s[r] = __expf(s[r] - m);
      ps += s[r];
    }
    ps += __shfl_xor(ps, 32);
    lsum += ps;

    // ---- P -> in-register A-fragments (cvt_pk + permlane32_swap) ----
    unsigned wh[8], wl2[8];
#pragma unroll
    for (int i = 0; i < 8; ++i) {
      float p0 = s[2 * i], p1 = s[2 * i + 1];
      unsigned hw;
      asm("v_cvt_pk_bf16_f32 %0, %1, %2" : "=v"(hw) : "v"(p0), "v"(p1));
      float h0 = __builtin_bit_cast(float, hw << 16);
      float h1 = __builtin_bit_cast(float, hw & 0xffff0000u);
      float r0 = p0 - h0, r1 = p1 - h1;
      unsigned lw;
      asm("v_cvt_pk_bf16_f32 %0, %1, %2" : "=v"(lw) : "v"(r0), "v"(r1));
      wh[i] = hw;
      wl2[i] = lw;
    }
    asm("v_permlane32_swap_b32 %0, %1" : "+v"(wh[0]), "+v"(wh[2]));
    asm("v_permlane32_swap_b32 %0, %1" : "+v"(wh[1]), "+v"(wh[3]));
    asm("v_permlane32_swap_b32 %0, %1" : "+v"(wh[4]), "+v"(wh[6]));
    asm("v_permlane32_swap_b32 %0, %1" : "+v"(wh[5]), "+v"(wh[7]));
    asm("v_permlane32_swap_b32 %0, %1" : "+v"(wl2[0]), "+v"(wl2[2]));
    asm("v_permlane32_swap_b32 %0, %1" : "+v"(wl2[1]), "+v"(wl2[3]));
    asm("v_permlane32_swap_b32 %0, %1" : "+v"(wl2[4]), "+v"(wl2[6]));
    asm("v_permlane32_swap_b32 %0, %1" : "+v"(wl2[5]), "+v"(wl2[7]));
    bfrag ph[2], pl[2];
    {
      uvec4 u0 = {wh[0], wh[1], wh[2], wh[3]};
      uvec4 u1 = {wh[4], wh[5], wh[6], wh[7]};
      uvec4 u2 = {wl2[0], wl2[1], wl2[2], wl2[3]};
      uvec4 u3 = {wl2[4], wl2[5], wl2[6], wl2[7]};
      ph[0] = __builtin_bit_cast(bfrag, u0);
      ph[1] = __builtin_bit_cast(bfrag, u1);
      pl[0] = __builtin_bit_cast(bfrag, u2);
      pl[1] = __builtin_bit_cast(bfrag, u3);
    }

    // ---- PV: o += P * V (A=P, B=V); V from LDS (staged, conflict-free) ----
#pragma unroll
    for (int ks = 0; ks < 2; ++ks) {
      const int vo = ((2 * ks + hi5) * 64 + l31) * 8;
      bfrag vh0 = *(const bfrag*)(t0 + 4096 + vo);
      bfrag vl0 = *(const bfrag*)(t0 + 6144 + vo);
      bfrag vh1 = *(const bfrag*)(t0 + 4096 + vo + 256);
      bfrag vl1 = *(const bfrag*)(t0 + 6144 + vo + 256);
      o0 = __builtin_amdgcn_mfma_f32_32x32x16_bf16(ph[ks], vh0, o0, 0, 0, 0);
      o0 = __builtin_amdgcn_mfma_f32_32x32x16_bf16(ph[ks], vl0, o0, 0, 0, 0);
      o0 = __builtin_amdgcn_mfma_f32_32x32x16_bf16(pl[ks], vh0, o0, 0, 0, 0);
      o1 = __builtin_amdgcn_mfma_f32_32x32x16_bf16(ph[ks], vh1, o1, 0, 0, 0);
      o1 = __builtin_amdgcn_mfma_f32_32x32x16_bf16(ph[ks], vl1, o1, 0, 0, 0);
      o1 = __builtin_amdgcn_mfma_f32_32x32x16_bf16(pl[ks], vh1, o1, 0, 0, 0);
    }
  }

  // ---- per-wave epilogue (wave owns its 32 rows exclusively) ----
  if (nsl == 1) {  // no split: final output directly
    const float linv = 1.0f / lsum;
    float* ob = Out + ((size_t)b * SS + qt * 64 + w * 32) * DH;
#pragma unroll
    for (int r = 0; r < 16; ++r) {
      int row = (r & 3) + 8 * (r >> 2) + 4 * hi5;
      float li = __shfl(linv, row);
      ob[row * DH + l31]      = o0[r] * li;
      ob[row * DH + 32 + l31] = o1[r] * li;
    }
  } else {  // slice partial: unnormalized o + (m, lsum) per row
    const size_t base = (size_t)((b * 64 + qt) * nsl + slice);
    float* po = part_o + base * 4096 + w * 32 * 64;
#pragma unroll
    for (int r = 0; r < 16; ++r) {
      int row = (r & 3) + 8 * (r >> 2) + 4 * hi5;
      po[row * 64 + l31]      = o0[r];
      po[row * 64 + 32 + l31] = o1[r];
    }
    if (hi5 == 0) {
      part_ml[base * 128 + (w * 32 + l31) * 2 + 0] = m;
      part_ml[base * 128 + (w * 32 + l31) * 2 + 1] = lsum;
    }
  }
}

// ---------------- split-K combine (4 slices, 64-row tiles) ----------------
__global__ __launch_bounds__(256) void combine(
    const float* __restrict__ part_o, const float* __restrict__ part_ml,
    float* __restrict__ Out, int nsl) {
  const int blk = blockIdx.x;           // 512 tiles
  const int b = blk & 7, qt = blk >> 3; // qt 0..63
  const int row = threadIdx.x >> 2;          // 0..63
  const int seg = (threadIdx.x & 3) * 16;
  const size_t base = (size_t)(b * 64 + qt) * nsl;

  float ms[NSL], ls[NSL];
  float M = -1e30f;
#pragma unroll
  for (int s = 0; s < NSL; ++s) {
    ms[s] = part_ml[(base + s) * 128 + row * 2 + 0];
    ls[s] = part_ml[(base + s) * 128 + row * 2 + 1];
    M = fmaxf(M, ms[s]);
  }
  float L = 0.f;
#pragma unroll
  for (int s = 0; s < NSL; ++s) {
    ms[s] = __expf(ms[s] - M);   // weight (0 for empty slices: m=-1e30)
    L += ms[s] * ls[s];
  }
  const float linv = 1.0f / L;

  float4 acc[4];
#pragma unroll
  for (int j = 0; j < 4; ++j) acc[j] = make_float4(0.f, 0.f, 0.f, 0.f);
#pragma unroll
  for (int s = 0; s < NSL; ++s) {
    const float4* po =
        (const float4*)(part_o + (base + s) * 4096 + row * 64 + seg);
#pragma unroll
    for (int j = 0; j < 4; ++j) {
      float4 v = po[j];
      acc[j].x += ms[s] * v.x;
      acc[j].y += ms[s] * v.y;
      acc[j].z += ms[s] * v.z;
      acc[j].w += ms[s] * v.w;
    }
  }
  float4* op = (float4*)(Out + ((size_t)b * SS + qt * 64 + row) * DH + seg);
#pragma unroll
  for (int j = 0; j < 4; ++j) {
    acc[j].x *= linv; acc[j].y *= linv; acc[j].z *= linv; acc[j].w *= linv;
    op[j] = acc[j];
  }
}

// ---------------- emergency fallback (ws too small): naive flash ------------
__global__ __launch_bounds__(256) void attn_naive(
    const float* __restrict__ Q, const float* __restrict__ K,
    const float* __restrict__ V, const int* __restrict__ VL,
    float* __restrict__ Out) {
  const int row = blockIdx.x * 256 + threadIdx.x;
  const int b = row >> 12;
  const int vlen = VL[b];
  const float* q = Q + (size_t)row * DH;
  float qr[DH];
#pragma unroll
  for (int d = 0; d < DH; ++d) qr[d] = q[d] * 0.125f;
  float m = -1e30f, ls = 0.f, o[DH];
#pragma unroll
  for (int d = 0; d < DH; ++d) o[d] = 0.f;
  const float* Kb = K + (size_t)b * SS * DH;
  const float* Vb = V + (size_t)b * SS * DH;
  for (int k = 0; k < vlen; ++k) {
    float sc = 0.f;
    for (int d = 0; d < DH; ++d) sc += qr[d] * Kb[(size_t)k * DH + d];
    if (sc > m) {
      float scale = __expf(m - sc);
      m = sc;
      ls *= scale;
      for (int d = 0; d < DH; ++d) o[d] *= scale;
    }
    float pv = __expf(sc - m);
    ls += pv;
    for (int d = 0; d < DH; ++d) o[d] += pv * Vb[(size_t)k * DH + d];
  }
  for (int d = 0; d < DH; ++d) Out[(size_t)row * DH + d] = o[d] / ls;
}

extern "C" void kernel_launch(void* const* d_in, const int* in_sizes, int n_in,
                              void* d_out, int out_size, void* d_ws,
                              size_t ws_size, hipStream_t stream) {
  const float* Q  = (const float*)d_in[0];
  const float* K  = (const float*)d_in[1];
  const float* V  = (const float*)d_in[2];
  const int*   VL = (const int*)d_in[3];
  float* Out = (float*)d_out;

  const size_t pack_bytes = (size_t)BB * NKT * TILE_SHORTS * sizeof(short);  // 16 MB
  const size_t po_bytes   = (size_t)TPB * NSL * 4096 * sizeof(float);        // 32 MB
  const size_t pml_bytes  = (size_t)TPB * NSL * 128 * sizeof(float);         // 1 MB
  const size_t need_split = pack_bytes + po_bytes + pml_bytes;               // 49 MB

  if (ws_size >= need_split) {
    short* pack = (short*)d_ws;
    float* po   = (float*)((char*)d_ws + pack_bytes);
    float* pml  = (float*)((char*)d_ws + pack_bytes + po_bytes);
    prepack<<<dim3(BB * NKT), dim3(256), 0, stream>>>(K, V, pack);
    attn_mfma<<<dim3(TPB * NSL), dim3(128), 0, stream>>>(
        Q, pack, VL, Out, po, pml, NSL);
    combine<<<dim3(TPB), dim3(256), 0, stream>>>(po, pml, Out, NSL);
  } else if (ws_size >= pack_bytes) {
    short* pack = (short*)d_ws;
    prepack<<<dim3(BB * NKT), dim3(256), 0, stream>>>(K, V, pack);
    attn_mfma<<<dim3(TPB), dim3(128), 0, stream>>>(
        Q, pack, VL, Out, (float*)d_ws, (float*)d_ws, 1);
  } else {
    attn_naive<<<dim3(BB * SS / 256), dim3(256), 0, stream>>>(Q, K, V, VL, Out);
  }
}

// Round 10
// 179.329 us; speedup vs baseline: 1.0395x; 1.0395x over previous
//
#include <hip/hip_runtime.h>
#include <stdint.h>

// DotProductAttention, B=8 S=4096 D=64 fp32, key-masked at valid_len[b].
// v7 = v5 (best measured: 101.7us attn) + balanced key slicing (no dead
// blocks; work per block proportional to vlen) + s_setprio around MFMA
// clusters. Block structure, mapping, and iteration body are v5's verified
// code: 256 thr = 4 waves x 32 rows (128-row tile), 2x16KB LDS chunk dbuf,
// swapped QK^T (mfma(K,Q)), error-compensated bf16 hi/lo, in-register P via
// cvt_pk+permlane32_swap, defer-max online softmax. Partials always written;
// combine always merges 4 slices (empty slices get weight exp(-1e30-M)=0).

constexpr int BB = 8;
constexpr int SS = 4096;
constexpr int DH = 64;
constexpr int CH = 32;              // keys per chunk
constexpr int NKT = SS / CH;        // 128 chunks per batch
constexpr int TILE_SHORTS = 8192;   // 16 KB: Khi 4K | Klo 4K | Vhi 4K | Vlo 4K
constexpr int NTILE = BB * (SS / 128);  // 256 output tiles of 128 rows
constexpr int NSL = 4;              // key slices per tile

typedef short  bfrag  __attribute__((ext_vector_type(8)));   // 8 bf16
typedef float  f32x16 __attribute__((ext_vector_type(16)));
typedef unsigned int uvec4 __attribute__((ext_vector_type(4)));

__device__ __forceinline__ unsigned short f2bf(float x) {
  unsigned u = __builtin_bit_cast(unsigned, x);
  u += 0x7fffu + ((u >> 16) & 1u);   // RNE
  return (unsigned short)(u >> 16);
}
__device__ __forceinline__ float bf2f(unsigned short h) {
  return __builtin_bit_cast(float, ((unsigned)h) << 16);
}

// ---------------- pre-pass: split+tile K and V (verified) ----------------
__global__ __launch_bounds__(256) void prepack(
    const float* __restrict__ K, const float* __restrict__ V,
    short* __restrict__ ws) {
  const int b  = blockIdx.x >> 7;
  const int kt = blockIdx.x & 127;
  const int t  = threadIdx.x;
  short* tile = ws + (size_t)(b * NKT + kt) * TILE_SHORTS;

  {  // K unit t: d8 = t>>5, key = t&31
    const int d8 = t >> 5, key = t & 31;
    const float* src = K + ((size_t)b * SS + kt * CH + key) * DH + d8 * 8;
    float4 a = ((const float4*)src)[0];
    float4 c = ((const float4*)src)[1];
    float v[8] = {a.x, a.y, a.z, a.w, c.x, c.y, c.z, c.w};
    bfrag hi, lo;
#pragma unroll
    for (int j = 0; j < 8; ++j) {
      unsigned short h = f2bf(v[j]);
      hi[j] = (short)h;
      lo[j] = (short)f2bf(v[j] - bf2f(h));
    }
    *(bfrag*)(tile + t * 8)        = hi;
    *(bfrag*)(tile + 2048 + t * 8) = lo;
  }
  {  // V unit t: k8 = t>>6, d = t&63
    const int k8 = t >> 6, d = t & 63;
    const float* src = V + ((size_t)b * SS + kt * CH + k8 * 8) * DH + d;
    bfrag hi, lo;
#pragma unroll
    for (int j = 0; j < 8; ++j) {
      float x = src[j * DH];
      unsigned short h = f2bf(x);
      hi[j] = (short)h;
      lo[j] = (short)f2bf(x - bf2f(h));
    }
    *(bfrag*)(tile + 4096 + t * 8) = hi;
    *(bfrag*)(tile + 6144 + t * 8) = lo;
  }
}

// ---------------- main fused attention ----------------
__global__ __launch_bounds__(256, 4) void attn_mfma(
    const float* __restrict__ Q, const short* __restrict__ wsT,
    const int* __restrict__ VL, float* __restrict__ Out,
    float* __restrict__ part_o, float* __restrict__ part_ml, int nsl) {
  __shared__ __align__(16) short sKV[2][TILE_SHORTS];  // 32 KB double buffer

  const int blk = blockIdx.x;
  // v5's verified mapping: slice in low bits (4 slices of a tile -> 4 XCDs),
  // batch cycles every 8 blocks.
  const int b  = (blk >> 3) & 7;
  const int qs = ((blk >> 6) << 3) | (blk & 7);  // 0..127
  const int qt = qs >> 2;                        // 0..31 (128-row tile)
  const int slice = qs & 3;
  const int tid = threadIdx.x;
  const int w   = tid >> 6;   // wave = row group (w*32 rows)
  const int l   = tid & 63;
  const int hi5 = l >> 5;
  const int l31 = l & 31;

  const int vlen = VL[b];
  const int nch  = (vlen + CH - 1) / CH;
  // balanced slicing: every block active, work proportional to vlen
  const int c_lo = slice * nch / nsl;
  const int c_hi = (slice + 1) * nch / nsl;
  const int nchS = c_hi - c_lo;

  // ---- Q fragments (B-operand: col=l31=q-row), pre-scaled by 1/8 ----
  bfrag qh[4], ql[4];
  {
    const float* qsrc = Q + ((size_t)b * SS + qt * 128 + w * 32 + l31) * DH;
#pragma unroll
    for (int dt = 0; dt < 4; ++dt) {
      const float* pp = qsrc + dt * 16 + hi5 * 8;
      float4 a = ((const float4*)pp)[0];
      float4 c = ((const float4*)pp)[1];
      float v[8] = {a.x, a.y, a.z, a.w, c.x, c.y, c.z, c.w};
#pragma unroll
      for (int j = 0; j < 8; ++j) {
        float x = v[j] * 0.125f;
        unsigned short h = f2bf(x);
        qh[dt][j] = (short)h;
        ql[dt][j] = (short)f2bf(x - bf2f(h));
      }
    }
  }

  f32x16 o0, o1;
#pragma unroll
  for (int r = 0; r < 16; ++r) { o0[r] = 0.f; o1[r] = 0.f; }
  float m = -1e30f, lsum = 0.f;

  const short* tbase = wsT + (size_t)b * NKT * TILE_SHORTS;

  // stage chunk ci (16KB) into sKV[buf]: 4 passes x (256 thr x 16B)
  auto stage = [&](int ci, int buf) {
    const short* g = tbase + (size_t)ci * TILE_SHORTS;
#pragma unroll
    for (int j = 0; j < 4; ++j) {
      __builtin_amdgcn_global_load_lds(
          (const __attribute__((address_space(1))) void*)(g + (j * 256 + tid) * 8),
          (__attribute__((address_space(3))) void*)(&sKV[buf][(j * 256 + tid) * 8]),
          16, 0, 0);
    }
  };

  if (nchS > 0) stage(c_lo, 0);

  for (int t = 0; t < nchS; ++t) {
    __syncthreads();  // implicit vmcnt(0)+lgkmcnt(0): staged chunk ready
    const int ci  = c_lo + t;
    const int cur = t & 1;
    if (t + 1 < nchS) stage(ci + 1, cur ^ 1);  // prefetch under compute
    const short* t0 = &sKV[cur][0];

    // ---- QK^T: acc[key][qrow], A=K B=Q; two 6-chains ----
    f32x16 accA, accB;
#pragma unroll
    for (int r = 0; r < 16; ++r) { accA[r] = 0.f; accB[r] = 0.f; }
    __builtin_amdgcn_s_setprio(1);
#pragma unroll
    for (int dt = 0; dt < 4; ++dt) {
      bfrag kh = *(const bfrag*)(t0 + ((2 * dt + hi5) * 32 + l31) * 8);
      bfrag kl = *(const bfrag*)(t0 + 2048 + ((2 * dt + hi5) * 32 + l31) * 8);
      accA = __builtin_amdgcn_mfma_f32_32x32x16_bf16(kh, qh[dt], accA, 0, 0, 0);
      if (dt < 2)
        accA = __builtin_amdgcn_mfma_f32_32x32x16_bf16(kh, ql[dt], accA, 0, 0, 0);
      else
        accB = __builtin_amdgcn_mfma_f32_32x32x16_bf16(kh, ql[dt], accB, 0, 0, 0);
      accB = __builtin_amdgcn_mfma_f32_32x32x16_bf16(kl, qh[dt], accB, 0, 0, 0);
    }
    __builtin_amdgcn_s_setprio(0);
    float s[16];
#pragma unroll
    for (int r = 0; r < 16; ++r) s[r] = accA[r] + accB[r];

    // ---- mask tail keys ----
    const int c0 = ci * CH;
    if (c0 + CH > vlen) {
#pragma unroll
      for (int r = 0; r < 16; ++r) {
        int key = c0 + (r & 3) + 8 * (r >> 2) + 4 * hi5;
        if (key >= vlen) s[r] = -1e30f;
      }
    }

    // ---- online softmax (lane owns q-row l31) ----
    float cmax = s[0];
#pragma unroll
    for (int r = 1; r < 16; ++r) cmax = fmaxf(cmax, s[r]);
    cmax = fmaxf(cmax, __shfl_xor(cmax, 32));

    if (__any((int)(cmax > m + 8.0f))) {  // defer-max (T13)
      float mn = fmaxf(m, cmax);
      float sc2 = __expf(m - mn);
      m = mn;
      lsum *= sc2;
#pragma unroll
      for (int r = 0; r < 16; ++r) {
        float s2 = __shfl(sc2, (r & 3) + 8 * (r >> 2) + 4 * hi5);
        o0[r] *= s2;
        o1[r] *= s2;
      }
    }

    float ps = 0.f;
#pragma unroll
    for (int r = 0; r < 16; ++r) {
      s[r] = __expf(s[r] - m);
      ps += s[r];
    }
    ps += __shfl_xor(ps, 32);
    lsum += ps;

    // ---- P -> in-register A-fragments (cvt_pk + permlane32_swap) ----
    unsigned wh[8], wl2[8];
#pragma unroll
    for (int i = 0; i < 8; ++i) {
      float p0 = s[2 * i], p1 = s[2 * i + 1];
      unsigned hw;
      asm("v_cvt_pk_bf16_f32 %0, %1, %2" : "=v"(hw) : "v"(p0), "v"(p1));
      float h0 = __builtin_bit_cast(float, hw << 16);
      float h1 = __builtin_bit_cast(float, hw & 0xffff0000u);
      float r0 = p0 - h0, r1 = p1 - h1;
      unsigned lw;
      asm("v_cvt_pk_bf16_f32 %0, %1, %2" : "=v"(lw) : "v"(r0), "v"(r1));
      wh[i] = hw;
      wl2[i] = lw;
    }
    asm("v_permlane32_swap_b32 %0, %1" : "+v"(wh[0]), "+v"(wh[2]));
    asm("v_permlane32_swap_b32 %0, %1" : "+v"(wh[1]), "+v"(wh[3]));
    asm("v_permlane32_swap_b32 %0, %1" : "+v"(wh[4]), "+v"(wh[6]));
    asm("v_permlane32_swap_b32 %0, %1" : "+v"(wh[5]), "+v"(wh[7]));
    asm("v_permlane32_swap_b32 %0, %1" : "+v"(wl2[0]), "+v"(wl2[2]));
    asm("v_permlane32_swap_b32 %0, %1" : "+v"(wl2[1]), "+v"(wl2[3]));
    asm("v_permlane32_swap_b32 %0, %1" : "+v"(wl2[4]), "+v"(wl2[6]));
    asm("v_permlane32_swap_b32 %0, %1" : "+v"(wl2[5]), "+v"(wl2[7]));
    bfrag ph[2], pl[2];
    {
      uvec4 u0 = {wh[0], wh[1], wh[2], wh[3]};
      uvec4 u1 = {wh[4], wh[5], wh[6], wh[7]};
      uvec4 u2 = {wl2[0], wl2[1], wl2[2], wl2[3]};
      uvec4 u3 = {wl2[4], wl2[5], wl2[6], wl2[7]};
      ph[0] = __builtin_bit_cast(bfrag, u0);
      ph[1] = __builtin_bit_cast(bfrag, u1);
      pl[0] = __builtin_bit_cast(bfrag, u2);
      pl[1] = __builtin_bit_cast(bfrag, u3);
    }

    // ---- PV: o += P * V (A=P, B=V); V from LDS (staged, conflict-free) ----
    __builtin_amdgcn_s_setprio(1);
#pragma unroll
    for (int ks = 0; ks < 2; ++ks) {
      const int vo = ((2 * ks + hi5) * 64 + l31) * 8;
      bfrag vh0 = *(const bfrag*)(t0 + 4096 + vo);
      bfrag vl0 = *(const bfrag*)(t0 + 6144 + vo);
      bfrag vh1 = *(const bfrag*)(t0 + 4096 + vo + 256);
      bfrag vl1 = *(const bfrag*)(t0 + 6144 + vo + 256);
      o0 = __builtin_amdgcn_mfma_f32_32x32x16_bf16(ph[ks], vh0, o0, 0, 0, 0);
      o0 = __builtin_amdgcn_mfma_f32_32x32x16_bf16(ph[ks], vl0, o0, 0, 0, 0);
      o0 = __builtin_amdgcn_mfma_f32_32x32x16_bf16(pl[ks], vh0, o0, 0, 0, 0);
      o1 = __builtin_amdgcn_mfma_f32_32x32x16_bf16(ph[ks], vh1, o1, 0, 0, 0);
      o1 = __builtin_amdgcn_mfma_f32_32x32x16_bf16(ph[ks], vl1, o1, 0, 0, 0);
      o1 = __builtin_amdgcn_mfma_f32_32x32x16_bf16(pl[ks], vh1, o1, 0, 0, 0);
    }
    __builtin_amdgcn_s_setprio(0);
  }

  // ---- per-wave epilogue (wave owns its 32 rows exclusively) ----
  if (nsl == 1) {  // no split: final output directly
    const float linv = 1.0f / lsum;
    float* ob = Out + ((size_t)b * SS + qt * 128 + w * 32) * DH;
#pragma unroll
    for (int r = 0; r < 16; ++r) {
      int row = (r & 3) + 8 * (r >> 2) + 4 * hi5;
      float li = __shfl(linv, row);
      ob[row * DH + l31]      = o0[r] * li;
      ob[row * DH + 32 + l31] = o1[r] * li;
    }
  } else {  // slice partial: unnormalized o + (m, lsum) per row
    const size_t base = (size_t)((b * 32 + qt) * nsl + slice);
    float* po = part_o + base * 8192 + w * 32 * 64;
#pragma unroll
    for (int r = 0; r < 16; ++r) {
      int row = (r & 3) + 8 * (r >> 2) + 4 * hi5;
      po[row * 64 + l31]      = o0[r];
      po[row * 64 + 32 + l31] = o1[r];
    }
    if (hi5 == 0) {
      part_ml[base * 256 + (w * 32 + l31) * 2 + 0] = m;
      part_ml[base * 256 + (w * 32 + l31) * 2 + 1] = lsum;
    }
  }
}

// ---------------- split-K combine (4 slices, 128-row tiles, always-run) -----
__global__ __launch_bounds__(256) void combine(
    const float* __restrict__ part_o, const float* __restrict__ part_ml,
    float* __restrict__ Out) {
  const int blk = blockIdx.x;           // 256 tiles
  const int b = blk & 7, qt = blk >> 3; // qt 0..31
  const int row = threadIdx.x >> 1;          // 0..127
  const int seg = (threadIdx.x & 1) * 32;    // half-row of 32 floats
  const size_t base = (size_t)(b * 32 + qt) * NSL;

  float ms[NSL], ls[NSL];
  float M = -1e30f;
#pragma unroll
  for (int s = 0; s < NSL; ++s) {
    ms[s] = part_ml[(base + s) * 256 + row * 2 + 0];
    ls[s] = part_ml[(base + s) * 256 + row * 2 + 1];
    M = fmaxf(M, ms[s]);
  }
  float L = 0.f;
#pragma unroll
  for (int s = 0; s < NSL; ++s) {
    ms[s] = __expf(ms[s] - M);   // weight; empty slice (m=-1e30) -> 0
    L += ms[s] * ls[s];
  }
  const float linv = 1.0f / L;

  float4 acc[8];
#pragma unroll
  for (int j = 0; j < 8; ++j) acc[j] = make_float4(0.f, 0.f, 0.f, 0.f);
#pragma unroll
  for (int s = 0; s < NSL; ++s) {
    const float4* po =
        (const float4*)(part_o + (base + s) * 8192 + row * 64 + seg);
#pragma unroll
    for (int j = 0; j < 8; ++j) {
      float4 v = po[j];
      acc[j].x += ms[s] * v.x;
      acc[j].y += ms[s] * v.y;
      acc[j].z += ms[s] * v.z;
      acc[j].w += ms[s] * v.w;
    }
  }
  float4* op = (float4*)(Out + ((size_t)b * SS + qt * 128 + row) * DH + seg);
#pragma unroll
  for (int j = 0; j < 8; ++j) {
    acc[j].x *= linv; acc[j].y *= linv; acc[j].z *= linv; acc[j].w *= linv;
    op[j] = acc[j];
  }
}

// ---------------- emergency fallback (ws too small): naive flash ------------
__global__ __launch_bounds__(256) void attn_naive(
    const float* __restrict__ Q, const float* __restrict__ K,
    const float* __restrict__ V, const int* __restrict__ VL,
    float* __restrict__ Out) {
  const int row = blockIdx.x * 256 + threadIdx.x;
  const int b = row >> 12;
  const int vlen = VL[b];
  const float* q = Q + (size_t)row * DH;
  float qr[DH];
#pragma unroll
  for (int d = 0; d < DH; ++d) qr[d] = q[d] * 0.125f;
  float m = -1e30f, ls = 0.f, o[DH];
#pragma unroll
  for (int d = 0; d < DH; ++d) o[d] = 0.f;
  const float* Kb = K + (size_t)b * SS * DH;
  const float* Vb = V + (size_t)b * SS * DH;
  for (int k = 0; k < vlen; ++k) {
    float sc = 0.f;
    for (int d = 0; d < DH; ++d) sc += qr[d] * Kb[(size_t)k * DH + d];
    if (sc > m) {
      float scale = __expf(m - sc);
      m = sc;
      ls *= scale;
      for (int d = 0; d < DH; ++d) o[d] *= scale;
    }
    float pv = __expf(sc - m);
    ls += pv;
    for (int d = 0; d < DH; ++d) o[d] += pv * Vb[(size_t)k * DH + d];
  }
  for (int d = 0; d < DH; ++d) Out[(size_t)row * DH + d] = o[d] / ls;
}

extern "C" void kernel_launch(void* const* d_in, const int* in_sizes, int n_in,
                              void* d_out, int out_size, void* d_ws,
                              size_t ws_size, hipStream_t stream) {
  const float* Q  = (const float*)d_in[0];
  const float* K  = (const float*)d_in[1];
  const float* V  = (const float*)d_in[2];
  const int*   VL = (const int*)d_in[3];
  float* Out = (float*)d_out;

  const size_t pack_bytes = (size_t)BB * NKT * TILE_SHORTS * sizeof(short);  // 16 MB
  const size_t po_bytes   = (size_t)NTILE * NSL * 8192 * sizeof(float);      // 32 MB
  const size_t pml_bytes  = (size_t)NTILE * NSL * 256 * sizeof(float);       // 1 MB
  const size_t need_split = pack_bytes + po_bytes + pml_bytes;               // 49 MB

  if (ws_size >= need_split) {
    short* pack = (short*)d_ws;
    float* po   = (float*)((char*)d_ws + pack_bytes);
    float* pml  = (float*)((char*)d_ws + pack_bytes + po_bytes);
    prepack<<<dim3(BB * NKT), dim3(256), 0, stream>>>(K, V, pack);
    attn_mfma<<<dim3(NTILE * NSL), dim3(256), 0, stream>>>(
        Q, pack, VL, Out, po, pml, NSL);
    combine<<<dim3(NTILE), dim3(256), 0, stream>>>(po, pml, Out);
  } else if (ws_size >= pack_bytes) {
    short* pack = (short*)d_ws;
    prepack<<<dim3(BB * NKT), dim3(256), 0, stream>>>(K, V, pack);
    attn_mfma<<<dim3(NTILE), dim3(256), 0, stream>>>(
        Q, pack, VL, Out, (float*)d_ws, (float*)d_ws, 1);
  } else {
    attn_naive<<<dim3(BB * SS / 256), dim3(256), 0, stream>>>(Q, K, V, VL, Out);
  }
}